// Round 7
// baseline (643.491 us; speedup 1.0000x reference)
//
#include <hip/hip_runtime.h>
#include <cstdint>
#include <cstddef>

#define Bb 2
#define Ss 2048
#define Dd 1024
#define Hh 16
#define NBLK 512

typedef __attribute__((ext_vector_type(8))) short short8;
typedef __attribute__((ext_vector_type(4))) short short4v;
typedef __attribute__((ext_vector_type(4))) float float4v;

__device__ inline short f2bf(float f) {
  unsigned u = __builtin_bit_cast(unsigned, f);
  u = (u + 0x7fffu + ((u >> 16) & 1u)) >> 16;
  return (short)u;
}

__device__ inline float bf2f(short s) {
  unsigned u = ((unsigned)(unsigned short)s) << 16;
  return __builtin_bit_cast(float, u);
}

__device__ inline void gl_lds16(const void* g, void* l) {
  __builtin_amdgcn_global_load_lds(
      (__attribute__((address_space(1))) void*)(void*)(g),
      (__attribute__((address_space(3))) void*)(l), 16, 0, 0);
}

#define MFMA(a, b, c) __builtin_amdgcn_mfma_f32_16x16x32_bf16((a), (b), (c), 0, 0, 0)

// ---------------- device-scope grid barrier (one-shot counter, pre-zeroed) ----
__device__ inline void gridbar(unsigned* bar, unsigned target) {
  __syncthreads();
  if (threadIdx.x == 0) {
    __threadfence();  // release: wb dirty L2 (agent scope spans XCDs)
    __hip_atomic_fetch_add(bar, 1u, __ATOMIC_RELEASE, __HIP_MEMORY_SCOPE_AGENT);
    while (__hip_atomic_load(bar, __ATOMIC_ACQUIRE, __HIP_MEMORY_SCOPE_AGENT) < target)
      __builtin_amdgcn_s_sleep(16);
    __threadfence();  // acquire: invalidate L1/L2 before consumer loads
  }
  __syncthreads();
}

// ---------------- LN row body (f32 in -> bf16 out), smem = 8 floats ----------
__device__ __forceinline__ void ln_row(const float* __restrict__ x,
                                       const float* __restrict__ g,
                                       const float* __restrict__ be,
                                       short* __restrict__ out, int row,
                                       float* red) {
  int tid = threadIdx.x;
  const float4* xr = (const float4*)(x + (size_t)row * Dd);
  float4 v = xr[tid];
  float s = v.x + v.y + v.z + v.w;
  float q = v.x * v.x + v.y * v.y + v.z * v.z + v.w * v.w;
#pragma unroll
  for (int off = 1; off < 64; off <<= 1) {
    s += __shfl_xor(s, off);
    q += __shfl_xor(q, off);
  }
  int w = tid >> 6;
  if ((tid & 63) == 0) { red[w] = s; red[4 + w] = q; }
  __syncthreads();
  s = red[0] + red[1] + red[2] + red[3];
  q = red[4] + red[5] + red[6] + red[7];
  float mu = s * (1.0f / Dd);
  float var = q * (1.0f / Dd) - mu * mu;
  float rstd = rsqrtf(var + 1e-5f);
  float4 gv = ((const float4*)g)[tid], bv = ((const float4*)be)[tid];
  short4v o;
  o.x = f2bf((v.x - mu) * rstd * gv.x + bv.x);
  o.y = f2bf((v.y - mu) * rstd * gv.y + bv.y);
  o.z = f2bf((v.z - mu) * rstd * gv.z + bv.z);
  o.w = f2bf((v.w - mu) * rstd * gv.w + bv.w);
  *(short4v*)(out + (size_t)row * Dd + tid * 4) = o;
  __syncthreads();  // protect red[] for next loop iteration
}

// ---------------- prep: 4 weight transposes + LN1, by block range ------------
__global__ __launch_bounds__(256) void prep_kernel(
    const float* __restrict__ W0, short* __restrict__ T0,
    const float* __restrict__ W1, short* __restrict__ T1,
    const float* __restrict__ W2, short* __restrict__ T2,
    const float* __restrict__ W3, short* __restrict__ T3,
    const float* __restrict__ x, const float* __restrict__ g1,
    const float* __restrict__ be1, short* __restrict__ h1) {
  __shared__ __align__(16) float t[32][33];
  int id = blockIdx.x;
  if (id >= 12288) {
    ln_row(x, g1, be1, h1, id - 12288, &t[0][0]);
    return;
  }
  const float* W; short* Wt; int N, K, tix;
  if (id < 3072)      { W = W0; Wt = T0; N = 3072; K = 1024; tix = id; }
  else if (id < 4096) { W = W1; Wt = T1; N = 1024; K = 1024; tix = id - 3072; }
  else if (id < 8192) { W = W2; Wt = T2; N = 4096; K = 1024; tix = id - 4096; }
  else                { W = W3; Wt = T3; N = 1024; K = 4096; tix = id - 8192; }
  int nx = N / 32;
  int n0 = (tix % nx) * 32, k0 = (tix / nx) * 32;
  int tx = threadIdx.x & 31, ty = threadIdx.x >> 5;
#pragma unroll
  for (int i = 0; i < 4; i++)
    t[ty + 8 * i][tx] = W[(size_t)(k0 + ty + 8 * i) * N + n0 + tx];
  __syncthreads();
#pragma unroll
  for (int i = 0; i < 4; i++)
    Wt[(size_t)(n0 + ty + 8 * i) * K + k0 + tx] = f2bf(t[tx][ty + 8 * i]);
}

// ---------------- transpose V part of qkv -> Vt[bh][d][s] (bf16) -------------
__global__ __launch_bounds__(256) void vt_kernel(const short* __restrict__ qkv,
                                                 short* __restrict__ Vt) {
  __shared__ short t[32][34];
  int s0 = blockIdx.x * 32;
  int d0 = blockIdx.y * 32;
  int bh = blockIdx.z;
  int b = bh >> 4, h = bh & 15;
  int tx = threadIdx.x & 31, ty = threadIdx.x >> 5;
#pragma unroll
  for (int i = 0; i < 4; i++)
    t[ty + 8 * i][tx] =
        qkv[(size_t)(b * Ss + s0 + ty + 8 * i) * 3072 + 2048 + h * 64 + d0 + tx];
  __syncthreads();
#pragma unroll
  for (int i = 0; i < 4; i++)
    Vt[(size_t)(bh * 64 + d0 + ty + 8 * i) * Ss + s0 + tx] = t[tx][ty + 8 * i];
}

// ---------------- 128x128 bf16 MFMA GEMM tile, BK=64, XOR-swizzled LDS -------
// MODE 0: bf16 out = acc+bias; MODE 2: bf16 out = gelu(acc+bias);
// MODE 3: bf16 partial at outp + zp*M*N
template <int MODE>
__device__ __forceinline__ void gemm_tile(const short* __restrict__ A,
                                          const short* __restrict__ Bt,
                                          const float* __restrict__ bias,
                                          void* __restrict__ outp,
                                          int M, int N, int K,
                                          int m0, int n0, int zp,
                                          int ks, int ke, char* smem) {
  short* As = (short*)smem;
  short* Bs = (short*)smem + 128 * 64;
  const int tid = threadIdx.x;
  const int w = tid >> 6, lane = tid & 63;
  const int sr = lane >> 3;
  const int sc = lane & 7;
  const int gc = sc ^ sr;
  const int fr = lane & 15;
  const int g = lane >> 4;
  const int wm = (w >> 1) * 64, wn = (w & 1) * 64;
  float4v acc[4][4] = {};
  const short* Ag = A + (size_t)(m0 + w * 32 + sr) * K + gc * 8;
  const short* Bg = Bt + (size_t)(n0 + w * 32 + sr) * K + gc * 8;
  short* Asw = As + (w * 32 + sr) * 64 + sc * 8;
  short* Bsw = Bs + (w * 32 + sr) * 64 + sc * 8;
  for (int k0 = ks; k0 < ke; k0 += 64) {
    __syncthreads();
#pragma unroll
    for (int i = 0; i < 4; i++) {
      gl_lds16(Ag + (size_t)(i * 8) * K + k0, Asw + i * 8 * 64);
      gl_lds16(Bg + (size_t)(i * 8) * K + k0, Bsw + i * 8 * 64);
    }
    __syncthreads();
#pragma unroll
    for (int kh = 0; kh < 2; kh++) {
      short8 a[4], b[4];
#pragma unroll
      for (int i = 0; i < 4; i++) {
        int row = wm + i * 16 + fr;
        int slot = (g + kh * 4) ^ (row & 7);
        a[i] = *(const short8*)(As + row * 64 + slot * 8);
      }
#pragma unroll
      for (int j = 0; j < 4; j++) {
        int row = wn + j * 16 + fr;
        int slot = (g + kh * 4) ^ (row & 7);
        b[j] = *(const short8*)(Bs + row * 64 + slot * 8);
      }
#pragma unroll
      for (int i = 0; i < 4; i++)
#pragma unroll
        for (int j = 0; j < 4; j++)
          acc[i][j] = MFMA(a[i], b[j], acc[i][j]);
    }
  }
  const int crow = g * 4;
  const int ccol = fr;
#pragma unroll
  for (int i = 0; i < 4; i++) {
#pragma unroll
    for (int j = 0; j < 4; j++) {
      int col = n0 + wn + j * 16 + ccol;
      float bcol = (MODE == 3) ? 0.f : bias[col];
#pragma unroll
      for (int r = 0; r < 4; r++) {
        int row = m0 + wm + i * 16 + crow + r;
        float v = acc[i][j][r] + bcol;
        if (MODE == 0) {
          ((short*)outp)[(size_t)row * N + col] = f2bf(v);
        } else if (MODE == 2) {
          float y = 0.79788456f * (v + 0.044715f * v * v * v);
          float e = __builtin_amdgcn_exp2f(y * 2.885390082f);
          float th = 1.0f - 2.0f * __builtin_amdgcn_rcpf(e + 1.0f);
          v = 0.5f * v * (1.0f + th);
          ((short*)outp)[(size_t)row * N + col] = f2bf(v);
        } else {
          short* pp = (short*)outp + (size_t)zp * M * N;
          pp[(size_t)row * N + col] = f2bf(v);
        }
      }
    }
  }
}

// ---------------- standalone qkv GEMM (768 blocks, XCD-patched) --------------
__global__ __launch_bounds__(256) void k_gemm_qkv(const short* __restrict__ A,
                                                  const short* __restrict__ Bt,
                                                  const float* __restrict__ bias,
                                                  short* __restrict__ o) {
  __shared__ __align__(16) char smem[32768];
  int t = blockIdx.x;
  int c8 = t & 7, tt = t >> 3;                 // per-XCD patch: 12n x 8m
  int m0 = ((c8 >> 1) * 8 + tt / 12) * 128;
  int n0 = ((c8 & 1) * 12 + tt % 12) * 128;
  gemm_tile<0>(A, Bt, bias, o, 4096, 3072, 1024, m0, n0, 0, 0, 1024, smem);
}

// ---------------- flash attention (unchanged, 1024 blocks) -------------------
__global__ __launch_bounds__(256) void flash_kernel(const short* __restrict__ qkv,
                                                    const short* __restrict__ Vt,
                                                    short* __restrict__ att) {
  __shared__ __align__(16) short Ks[4096];
  __shared__ __align__(16) short Vs[4096];
  __shared__ __align__(16) short P[4][16 * 72];
  const int w = threadIdx.x >> 6, lane = threadIdx.x & 63;
  const int qb = 31 - (blockIdx.x >> 5);
  const int bh = blockIdx.x & 31;
  const int b = bh >> 4, h = bh & 15;
  const int qbase = qb * 64 + w * 16;
  const int q = lane & 15;
  const int g = lane >> 4;
  const int fk = g * 8;
  short* Pw = &P[w][0];

  const int L0 = w * 64 + lane, L1 = L0 + 256;
  const int r0 = L0 >> 3, c0 = (L0 & 7) ^ (r0 & 7);
  const int r1 = L1 >> 3, c1 = (L1 & 7) ^ (r1 & 7);
  const short* kg0 = qkv + (size_t)(b * Ss + r0) * 3072 + 1024 + h * 64 + c0 * 8;
  const short* kg1 = qkv + (size_t)(b * Ss + r1) * 3072 + 1024 + h * 64 + c1 * 8;
  const short* vg0 = Vt + (size_t)(bh * 64 + r0) * Ss + c0 * 8;
  const short* vg1 = Vt + (size_t)(bh * 64 + r1) * Ss + c1 * 8;

  short8 qf[2];
  {
    const short* qrow = qkv + (size_t)(b * Ss + qbase + q) * 3072 + h * 64;
    qf[0] = *(const short8*)(qrow + fk);
    qf[1] = *(const short8*)(qrow + 32 + fk);
  }
  float4v o[4] = {};
  float l_i = 0.f;
  const float sc = 0.125f * 1.44269504088896f;
  const int nkt = qb + 1;

  for (int kt = 0; kt < nkt; kt++) {
    const int kbase = kt * 64;
    __syncthreads();
    gl_lds16(kg0 + (size_t)kbase * 3072, Ks + L0 * 8);
    gl_lds16(kg1 + (size_t)kbase * 3072, Ks + L1 * 8);
    gl_lds16(vg0 + kbase, Vs + L0 * 8);
    gl_lds16(vg1 + kbase, Vs + L1 * 8);
    __syncthreads();

    short8 kf[4][2], vf[4][2];
#pragma unroll
    for (int t = 0; t < 4; t++) {
      const int row = 16 * t + q;
      const int sw = (g ^ (row & 7)) * 8;
      kf[t][0] = *(const short8*)(Ks + row * 64 + sw);
      kf[t][1] = *(const short8*)(Ks + row * 64 + (sw ^ 32));
      vf[t][0] = *(const short8*)(Vs + row * 64 + sw);
      vf[t][1] = *(const short8*)(Vs + row * 64 + (sw ^ 32));
    }
    float4v s[4] = {};
#pragma unroll
    for (int t = 0; t < 4; t++) {
      s[t] = MFMA(kf[t][0], qf[0], s[t]);
      s[t] = MFMA(kf[t][1], qf[1], s[t]);
    }
    const bool maskt = (kbase + 63 > qbase);
    const int qlim = qbase + q - kbase;
    float p[4][4];
    float rs = 0.f;
#pragma unroll
    for (int t = 0; t < 4; t++) {
#pragma unroll
      for (int r = 0; r < 4; r++) {
        float v = s[t][r] * sc;
        if (maskt && (16 * t + 4 * g + r > qlim)) v = -3.0e38f;
        float e = __builtin_amdgcn_exp2f(v);
        p[t][r] = e;
        rs += e;
      }
    }
    rs += __shfl_xor(rs, 16);
    rs += __shfl_xor(rs, 32);
    l_i += rs;
#pragma unroll
    for (int t = 0; t < 4; t++) {
      unsigned lo = (unsigned)(unsigned short)f2bf(p[t][0]) |
                    ((unsigned)(unsigned short)f2bf(p[t][1]) << 16);
      unsigned hi = (unsigned)(unsigned short)f2bf(p[t][2]) |
                    ((unsigned)(unsigned short)f2bf(p[t][3]) << 16);
      uint2 u; u.x = lo; u.y = hi;
      *(uint2*)(Pw + q * 72 + 16 * t + 4 * g) = u;
    }
    asm volatile("s_waitcnt lgkmcnt(0)" ::: "memory");
    short8 pb0 = *(const short8*)(Pw + q * 72 + fk);
    short8 pb1 = *(const short8*)(Pw + q * 72 + 32 + fk);
#pragma unroll
    for (int t = 0; t < 4; t++) {
      o[t] = MFMA(vf[t][0], pb0, o[t]);
      o[t] = MFMA(vf[t][1], pb1, o[t]);
    }
  }
  const float inv = 1.0f / l_i;
  const int orow = b * Ss + qbase + q;
#pragma unroll
  for (int t = 0; t < 4; t++) {
    short4v ov;
    ov.x = f2bf(o[t][0] * inv);
    ov.y = f2bf(o[t][1] * inv);
    ov.z = f2bf(o[t][2] * inv);
    ov.w = f2bf(o[t][3] * inv);
    *(short4v*)(att + (size_t)orow * Dd + h * 64 + 16 * t + 4 * g) = ov;
  }
}

// ---------------- mega2: wo | B | reduce+LN2 | B | fc | B | pr | B | reduce ---
__global__ __launch_bounds__(256, 2) void mega2(
    const float* __restrict__ x, const float* __restrict__ bo,
    const float* __restrict__ g2, const float* __restrict__ be2,
    const float* __restrict__ bfc, const float* __restrict__ bpr,
    const short* __restrict__ att, const short* __restrict__ WtO,
    const short* __restrict__ WtFc, const short* __restrict__ WtPr,
    short* __restrict__ partWo, float* __restrict__ x1, short* __restrict__ h2,
    short* __restrict__ geluo, short* __restrict__ partPr,
    float* __restrict__ out, unsigned* __restrict__ bar) {
  __shared__ __align__(16) char smem[32768];
  const int c = blockIdx.x;
  const int tid = threadIdx.x;

  // P0: Wo projection, split-K=2, bf16 partials; XCD patch 8n x 4m per z
  {
    int z = c >> 8, rem = c & 255;
    int c8 = rem & 7, tt = rem >> 3;
    int m0 = (c8 * 4 + tt / 8) * 128, n0 = (tt % 8) * 128;
    gemm_tile<3>(att, WtO, nullptr, partWo, 4096, 1024, 1024, m0, n0, z,
                 z * 512, z * 512 + 512, smem);
  }
  gridbar(bar + 0, NBLK);

  // P1: x1 = x + bo + partials; h2 = LN2(x1)
  for (int row = c; row < 4096; row += NBLK) {
    size_t base = (size_t)row * Dd + tid * 4;
    float4 v = *(const float4*)(x + base);
    float4 bv = ((const float4*)bo)[tid];
    v.x += bv.x; v.y += bv.y; v.z += bv.z; v.w += bv.w;
#pragma unroll
    for (int s = 0; s < 2; s++) {
      short4v p = *(const short4v*)(partWo + (size_t)s * 4096 * Dd + base);
      v.x += bf2f(p.x); v.y += bf2f(p.y); v.z += bf2f(p.z); v.w += bf2f(p.w);
    }
    *(float4*)(x1 + base) = v;
    float s = v.x + v.y + v.z + v.w;
    float q = v.x * v.x + v.y * v.y + v.z * v.z + v.w * v.w;
#pragma unroll
    for (int off = 1; off < 64; off <<= 1) {
      s += __shfl_xor(s, off);
      q += __shfl_xor(q, off);
    }
    float* red = (float*)smem;
    int w = tid >> 6;
    if ((tid & 63) == 0) { red[w] = s; red[4 + w] = q; }
    __syncthreads();
    s = red[0] + red[1] + red[2] + red[3];
    q = red[4] + red[5] + red[6] + red[7];
    float mu = s * (1.0f / Dd);
    float var = q * (1.0f / Dd) - mu * mu;
    float rstd = rsqrtf(var + 1e-5f);
    float4 gv = ((const float4*)g2)[tid], b2 = ((const float4*)be2)[tid];
    short4v o;
    o.x = f2bf((v.x - mu) * rstd * gv.x + b2.x);
    o.y = f2bf((v.y - mu) * rstd * gv.y + b2.y);
    o.z = f2bf((v.z - mu) * rstd * gv.z + b2.z);
    o.w = f2bf((v.w - mu) * rstd * gv.w + b2.w);
    *(short4v*)(h2 + base) = o;
    __syncthreads();
  }
  gridbar(bar + 16, NBLK);

  // P2: fc GEMM + GELU; 1024 tiles, 2 rounds; XCD patch 16n x 8m
  for (int t = c; t < 1024; t += NBLK) {
    int c8 = t & 7, tt = t >> 3;
    int m0 = ((c8 >> 1) * 8 + tt / 16) * 128;
    int n0 = ((c8 & 1) * 16 + tt % 16) * 128;
    gemm_tile<2>(h2, WtFc, bfc, geluo, 4096, 4096, 1024, m0, n0, 0, 0, 1024, smem);
  }
  gridbar(bar + 32, NBLK);

  // P3: pr projection, split-K=2, bf16 partials; XCD patch 8n x 4m per z
  {
    int z = c >> 8, rem = c & 255;
    int c8 = rem & 7, tt = rem >> 3;
    int m0 = (c8 * 4 + tt / 8) * 128, n0 = (tt % 8) * 128;
    gemm_tile<3>(geluo, WtPr, nullptr, partPr, 4096, 1024, 4096, m0, n0, z,
                 z * 2048, z * 2048 + 2048, smem);
  }
  gridbar(bar + 48, NBLK);

  // P4: out = x1 + bpr + partials
  for (int row = c; row < 4096; row += NBLK) {
    size_t base = (size_t)row * Dd + tid * 4;
    float4 v = *(const float4*)(x1 + base);
    float4 bv = ((const float4*)bpr)[tid];
    v.x += bv.x; v.y += bv.y; v.z += bv.z; v.w += bv.w;
#pragma unroll
    for (int s = 0; s < 2; s++) {
      short4v p = *(const short4v*)(partPr + (size_t)s * 4096 * Dd + base);
      v.x += bf2f(p.x); v.y += bf2f(p.y); v.z += bf2f(p.z); v.w += bf2f(p.w);
    }
    *(float4*)(out + base) = v;
  }
}

extern "C" void kernel_launch(void* const* d_in, const int* in_sizes, int n_in,
                              void* d_out, int out_size, void* d_ws, size_t ws_size,
                              hipStream_t stream) {
  const float* x    = (const float*)d_in[0];
  const float* Wqkv = (const float*)d_in[1];
  const float* bqkv = (const float*)d_in[2];
  const float* Wo   = (const float*)d_in[3];
  const float* bo   = (const float*)d_in[4];
  const float* Wfc  = (const float*)d_in[5];
  const float* bfc  = (const float*)d_in[6];
  const float* Wpr  = (const float*)d_in[7];
  const float* bpr  = (const float*)d_in[8];
  const float* g1   = (const float*)d_in[9];
  const float* be1  = (const float*)d_in[10];
  const float* g2   = (const float*)d_in[11];
  const float* be2  = (const float*)d_in[12];

  char* ws = (char*)d_ws;
  const size_t MB = 1024 * 1024;
  short* h1     = (short*)(ws + 0);        // [0,8)
  short* qkvb   = (short*)(ws + 8 * MB);   // [8,32)
  short* partWo = (short*)(ws + 0);        // [0,16), after flash
  short* partPr = (short*)(ws + 0);        // [0,16), after fc
  unsigned* bar = (unsigned*)(ws + 16 * MB);  // [16,16+4K): dead during mega2
  short* Vt     = (short*)(ws + 32 * MB);  // [32,40)
  short* att    = (short*)(ws + 40 * MB);  // [40,48)
  float* x1     = (float*)(ws + 48 * MB);  // [48,64)
  short* h2     = (short*)(ws + 64 * MB);  // [64,72)
  short* geluo  = (short*)(ws + 72 * MB);  // [72,104)
  short* WtQkv  = (short*)(ws + 104 * MB);
  short* WtO    = (short*)(ws + 110 * MB);
  short* WtFc   = (short*)(ws + 112 * MB);
  short* WtPr   = (short*)(ws + 120 * MB);

  prep_kernel<<<16384, 256, 0, stream>>>(Wqkv, WtQkv, Wo, WtO, Wfc, WtFc,
                                         Wpr, WtPr, x, g1, be1, h1);
  k_gemm_qkv<<<768, 256, 0, stream>>>(h1, WtQkv, bqkv, qkvb);
  vt_kernel<<<dim3(64, 2, 32), 256, 0, stream>>>(qkvb, Vt);
  flash_kernel<<<1024, 256, 0, stream>>>(qkvb, Vt, att);
  hipMemsetAsync(bar, 0, 4096, stream);  // barrier counters (region dead post-flash)
  mega2<<<NBLK, 256, 0, stream>>>(x, bo, g2, be2, bfc, bpr, att, WtO, WtFc,
                                  WtPr, partWo, x1, h2, geluo, partPr,
                                  (float*)d_out, bar);
}

// Round 8
// 330.797 us; speedup vs baseline: 1.9453x; 1.9453x over previous
//
#include <hip/hip_runtime.h>
#include <cstdint>
#include <cstddef>

#define Bb 2
#define Ss 2048
#define Dd 1024
#define Hh 16

typedef __attribute__((ext_vector_type(8))) short short8;
typedef __attribute__((ext_vector_type(4))) short short4v;
typedef __attribute__((ext_vector_type(4))) float float4v;

__device__ inline short f2bf(float f) {
  unsigned u = __builtin_bit_cast(unsigned, f);
  u = (u + 0x7fffu + ((u >> 16) & 1u)) >> 16;
  return (short)u;
}

__device__ inline float bf2f(short s) {
  unsigned u = ((unsigned)(unsigned short)s) << 16;
  return __builtin_bit_cast(float, u);
}

__device__ inline void gl_lds16(const void* g, void* l) {
  __builtin_amdgcn_global_load_lds(
      (__attribute__((address_space(1))) void*)(void*)(g),
      (__attribute__((address_space(3))) void*)(l), 16, 0, 0);
}

#define MFMA(a, b, c) __builtin_amdgcn_mfma_f32_16x16x32_bf16((a), (b), (c), 0, 0, 0)

// ---------------- LN row body (f32 in -> bf16 out) ----------------
__device__ __forceinline__ void ln_row(const float* __restrict__ x,
                                       const float* __restrict__ g,
                                       const float* __restrict__ be,
                                       short* __restrict__ out, int row,
                                       float* red) {
  int tid = threadIdx.x;
  const float4* xr = (const float4*)(x + (size_t)row * Dd);
  float4 v = xr[tid];
  float s = v.x + v.y + v.z + v.w;
  float q = v.x * v.x + v.y * v.y + v.z * v.z + v.w * v.w;
#pragma unroll
  for (int off = 1; off < 64; off <<= 1) {
    s += __shfl_xor(s, off);
    q += __shfl_xor(q, off);
  }
  int w = tid >> 6;
  if ((tid & 63) == 0) { red[w] = s; red[4 + w] = q; }
  __syncthreads();
  s = red[0] + red[1] + red[2] + red[3];
  q = red[4] + red[5] + red[6] + red[7];
  float mu = s * (1.0f / Dd);
  float var = q * (1.0f / Dd) - mu * mu;
  float rstd = rsqrtf(var + 1e-5f);
  float4 gv = ((const float4*)g)[tid], bv = ((const float4*)be)[tid];
  short4v o;
  o.x = f2bf((v.x - mu) * rstd * gv.x + bv.x);
  o.y = f2bf((v.y - mu) * rstd * gv.y + bv.y);
  o.z = f2bf((v.z - mu) * rstd * gv.z + bv.z);
  o.w = f2bf((v.w - mu) * rstd * gv.w + bv.w);
  *(short4v*)(out + (size_t)row * Dd + tid * 4) = o;
}

// ---------------- prep: 4 weight transposes + LN1, by block range ------------
__global__ __launch_bounds__(256) void prep_kernel(
    const float* __restrict__ W0, short* __restrict__ T0,
    const float* __restrict__ W1, short* __restrict__ T1,
    const float* __restrict__ W2, short* __restrict__ T2,
    const float* __restrict__ W3, short* __restrict__ T3,
    const float* __restrict__ x, const float* __restrict__ g1,
    const float* __restrict__ be1, short* __restrict__ h1) {
  __shared__ __align__(16) float t[32][33];
  int id = blockIdx.x;
  if (id >= 12288) {
    ln_row(x, g1, be1, h1, id - 12288, &t[0][0]);
    return;
  }
  const float* W; short* Wt; int N, K, tix;
  if (id < 3072)      { W = W0; Wt = T0; N = 3072; K = 1024; tix = id; }
  else if (id < 4096) { W = W1; Wt = T1; N = 1024; K = 1024; tix = id - 3072; }
  else if (id < 8192) { W = W2; Wt = T2; N = 4096; K = 1024; tix = id - 4096; }
  else                { W = W3; Wt = T3; N = 1024; K = 4096; tix = id - 8192; }
  int nx = N / 32;
  int n0 = (tix % nx) * 32, k0 = (tix / nx) * 32;
  int tx = threadIdx.x & 31, ty = threadIdx.x >> 5;
#pragma unroll
  for (int i = 0; i < 4; i++)
    t[ty + 8 * i][tx] = W[(size_t)(k0 + ty + 8 * i) * N + n0 + tx];
  __syncthreads();
#pragma unroll
  for (int i = 0; i < 4; i++)
    Wt[(size_t)(n0 + ty + 8 * i) * K + k0 + tx] = f2bf(t[tx][ty + 8 * i]);
}

// -------- fused: x1 = x + bias + p0 + p1 (f32), then h2 = LN2(x1) bf16 -------
__global__ __launch_bounds__(256) void reduce_ln_kernel(const float* __restrict__ x,
                                                        const float* __restrict__ bias,
                                                        const short* __restrict__ parts,
                                                        const float* __restrict__ g,
                                                        const float* __restrict__ be,
                                                        float* __restrict__ x1,
                                                        short* __restrict__ h2) {
  int row = blockIdx.x, tid = threadIdx.x;
  size_t base = (size_t)row * Dd + tid * 4;
  float4 v = *(const float4*)(x + base);
  float4 bv = ((const float4*)bias)[tid];
  v.x += bv.x; v.y += bv.y; v.z += bv.z; v.w += bv.w;
#pragma unroll
  for (int s = 0; s < 2; s++) {
    short4v p = *(const short4v*)(parts + (size_t)s * 4096 * Dd + base);
    v.x += bf2f(p.x); v.y += bf2f(p.y); v.z += bf2f(p.z); v.w += bf2f(p.w);
  }
  *(float4*)(x1 + base) = v;
  float s = v.x + v.y + v.z + v.w;
  float q = v.x * v.x + v.y * v.y + v.z * v.z + v.w * v.w;
#pragma unroll
  for (int off = 1; off < 64; off <<= 1) {
    s += __shfl_xor(s, off);
    q += __shfl_xor(q, off);
  }
  __shared__ float as_[4], aq_[4];
  int w = tid >> 6;
  if ((tid & 63) == 0) { as_[w] = s; aq_[w] = q; }
  __syncthreads();
  s = as_[0] + as_[1] + as_[2] + as_[3];
  q = aq_[0] + aq_[1] + aq_[2] + aq_[3];
  float mu = s * (1.0f / Dd);
  float var = q * (1.0f / Dd) - mu * mu;
  float rstd = rsqrtf(var + 1e-5f);
  float4 gv = ((const float4*)g)[tid], b2 = ((const float4*)be)[tid];
  short4v o;
  o.x = f2bf((v.x - mu) * rstd * gv.x + b2.x);
  o.y = f2bf((v.y - mu) * rstd * gv.y + b2.y);
  o.z = f2bf((v.z - mu) * rstd * gv.z + b2.z);
  o.w = f2bf((v.w - mu) * rstd * gv.w + b2.w);
  *(short4v*)(h2 + base) = o;
}

// ---------------- final reduce: dst = src + bias + sum(2 bf16 partials) ------
__global__ __launch_bounds__(256) void reduce_kernel(const float* __restrict__ src,
                                                     const float* __restrict__ bias,
                                                     const short* __restrict__ parts,
                                                     float* __restrict__ dst) {
  int row = blockIdx.x, tid = threadIdx.x;
  size_t base = (size_t)row * Dd + tid * 4;
  float4 v = *(const float4*)(src + base);
  float4 bv = ((const float4*)bias)[tid];
  v.x += bv.x; v.y += bv.y; v.z += bv.z; v.w += bv.w;
#pragma unroll
  for (int s = 0; s < 2; s++) {
    short4v p = *(const short4v*)(parts + (size_t)s * 4096 * Dd + base);
    v.x += bf2f(p.x); v.y += bf2f(p.y); v.z += bf2f(p.z); v.w += bf2f(p.w);
  }
  *(float4*)(dst + base) = v;
}

// ---------------- transpose V part of qkv -> Vt[bh][d][s] (bf16) -------------
__global__ __launch_bounds__(256) void vt_kernel(const short* __restrict__ qkv,
                                                 short* __restrict__ Vt) {
  __shared__ short t[32][34];
  int s0 = blockIdx.x * 32;
  int d0 = blockIdx.y * 32;
  int bh = blockIdx.z;
  int b = bh >> 4, h = bh & 15;
  int tx = threadIdx.x & 31, ty = threadIdx.x >> 5;
#pragma unroll
  for (int i = 0; i < 4; i++)
    t[ty + 8 * i][tx] =
        qkv[(size_t)(b * Ss + s0 + ty + 8 * i) * 3072 + 2048 + h * 64 + d0 + tx];
  __syncthreads();
#pragma unroll
  for (int i = 0; i < 4; i++)
    Vt[(size_t)(bh * 64 + d0 + ty + 8 * i) * Ss + s0 + tx] = t[tx][ty + 8 * i];
}

// ---------------- 128x128 bf16 MFMA GEMM tile, BK=64, XOR-swizzled LDS -------
// MODE 0: bf16 out = acc+bias; MODE 2: bf16 out = gelu(acc+bias);
// MODE 3: bf16 partial at outp + zp*M*N
template <int MODE>
__device__ __forceinline__ void gemm_tile(const short* __restrict__ A,
                                          const short* __restrict__ Bt,
                                          const float* __restrict__ bias,
                                          void* __restrict__ outp,
                                          int M, int N, int K,
                                          int m0, int n0, int zp,
                                          int ks, int ke, char* smem) {
  short* As = (short*)smem;
  short* Bs = (short*)smem + 128 * 64;
  const int tid = threadIdx.x;
  const int w = tid >> 6, lane = tid & 63;
  const int sr = lane >> 3;
  const int sc = lane & 7;
  const int gc = sc ^ sr;
  const int fr = lane & 15;
  const int g = lane >> 4;
  const int wm = (w >> 1) * 64, wn = (w & 1) * 64;
  float4v acc[4][4] = {};
  const short* Ag = A + (size_t)(m0 + w * 32 + sr) * K + gc * 8;
  const short* Bg = Bt + (size_t)(n0 + w * 32 + sr) * K + gc * 8;
  short* Asw = As + (w * 32 + sr) * 64 + sc * 8;
  short* Bsw = Bs + (w * 32 + sr) * 64 + sc * 8;
  for (int k0 = ks; k0 < ke; k0 += 64) {
    __syncthreads();
#pragma unroll
    for (int i = 0; i < 4; i++) {
      gl_lds16(Ag + (size_t)(i * 8) * K + k0, Asw + i * 8 * 64);
      gl_lds16(Bg + (size_t)(i * 8) * K + k0, Bsw + i * 8 * 64);
    }
    __syncthreads();
#pragma unroll
    for (int kh = 0; kh < 2; kh++) {
      short8 a[4], b[4];
#pragma unroll
      for (int i = 0; i < 4; i++) {
        int row = wm + i * 16 + fr;
        int slot = (g + kh * 4) ^ (row & 7);
        a[i] = *(const short8*)(As + row * 64 + slot * 8);
      }
#pragma unroll
      for (int j = 0; j < 4; j++) {
        int row = wn + j * 16 + fr;
        int slot = (g + kh * 4) ^ (row & 7);
        b[j] = *(const short8*)(Bs + row * 64 + slot * 8);
      }
#pragma unroll
      for (int i = 0; i < 4; i++)
#pragma unroll
        for (int j = 0; j < 4; j++)
          acc[i][j] = MFMA(a[i], b[j], acc[i][j]);
    }
  }
  const int crow = g * 4;
  const int ccol = fr;
#pragma unroll
  for (int i = 0; i < 4; i++) {
#pragma unroll
    for (int j = 0; j < 4; j++) {
      int col = n0 + wn + j * 16 + ccol;
      float bcol = (MODE == 3) ? 0.f : bias[col];
#pragma unroll
      for (int r = 0; r < 4; r++) {
        int row = m0 + wm + i * 16 + crow + r;
        float v = acc[i][j][r] + bcol;
        if (MODE == 0) {
          ((short*)outp)[(size_t)row * N + col] = f2bf(v);
        } else if (MODE == 2) {
          float y = 0.79788456f * (v + 0.044715f * v * v * v);
          float e = __builtin_amdgcn_exp2f(y * 2.885390082f);
          float th = 1.0f - 2.0f * __builtin_amdgcn_rcpf(e + 1.0f);
          v = 0.5f * v * (1.0f + th);
          ((short*)outp)[(size_t)row * N + col] = f2bf(v);
        } else {
          short* pp = (short*)outp + (size_t)zp * M * N;
          pp[(size_t)row * N + col] = f2bf(v);
        }
      }
    }
  }
}

// ---------------- qkv GEMM: 768 blocks, per-XCD 8m x 12n patch ---------------
__global__ __launch_bounds__(256) void k_gemm_qkv(const short* __restrict__ A,
                                                  const short* __restrict__ Bt,
                                                  const float* __restrict__ bias,
                                                  short* __restrict__ o) {
  __shared__ __align__(16) char smem[32768];
  int t = blockIdx.x;
  int c8 = t & 7, tt = t >> 3;
  int m0 = ((c8 >> 1) * 8 + tt / 12) * 128;
  int n0 = ((c8 & 1) * 12 + tt % 12) * 128;
  gemm_tile<0>(A, Bt, bias, o, 4096, 3072, 1024, m0, n0, 0, 0, 1024, smem);
}

// ---------------- fc GEMM+GELU: 1024 blocks, per-XCD 8m x 16n patch ----------
__global__ __launch_bounds__(256) void k_gemm_fc(const short* __restrict__ A,
                                                 const short* __restrict__ Bt,
                                                 const float* __restrict__ bias,
                                                 short* __restrict__ o) {
  __shared__ __align__(16) char smem[32768];
  int t = blockIdx.x;
  int c8 = t & 7, tt = t >> 3;
  int m0 = ((c8 >> 1) * 8 + tt / 16) * 128;
  int n0 = ((c8 & 1) * 16 + tt % 16) * 128;
  gemm_tile<2>(A, Bt, bias, o, 4096, 4096, 1024, m0, n0, 0, 0, 1024, smem);
}

// ---------------- wo projection: 512 blocks, split-K=2, 4m x 8n patch --------
__global__ __launch_bounds__(256) void k_gemm_wo(const short* __restrict__ A,
                                                 const short* __restrict__ Bt,
                                                 short* __restrict__ parts) {
  __shared__ __align__(16) char smem[32768];
  int c = blockIdx.x;
  int z = c >> 8, rem = c & 255;
  int c8 = rem & 7, tt = rem >> 3;
  int m0 = (c8 * 4 + tt / 8) * 128, n0 = (tt % 8) * 128;
  gemm_tile<3>(A, Bt, nullptr, parts, 4096, 1024, 1024, m0, n0, z,
               z * 512, z * 512 + 512, smem);
}

// ---------------- pr projection: 512 blocks, split-K=2, 4m x 8n patch --------
__global__ __launch_bounds__(256) void k_gemm_pr(const short* __restrict__ A,
                                                 const short* __restrict__ Bt,
                                                 short* __restrict__ parts) {
  __shared__ __align__(16) char smem[32768];
  int c = blockIdx.x;
  int z = c >> 8, rem = c & 255;
  int c8 = rem & 7, tt = rem >> 3;
  int m0 = (c8 * 4 + tt / 8) * 128, n0 = (tt % 8) * 128;
  gemm_tile<3>(A, Bt, nullptr, parts, 4096, 1024, 4096, m0, n0, z,
               z * 2048, z * 2048 + 2048, smem);
}

// ---------------- flash attention, block-cooperative K/V staging -------------
__global__ __launch_bounds__(256) void flash_kernel(const short* __restrict__ qkv,
                                                    const short* __restrict__ Vt,
                                                    short* __restrict__ att) {
  __shared__ __align__(16) short Ks[4096];
  __shared__ __align__(16) short Vs[4096];
  __shared__ __align__(16) short P[4][16 * 72];
  const int w = threadIdx.x >> 6, lane = threadIdx.x & 63;
  const int qb = 31 - (blockIdx.x >> 5);
  const int bh = blockIdx.x & 31;
  const int b = bh >> 4, h = bh & 15;
  const int qbase = qb * 64 + w * 16;
  const int q = lane & 15;
  const int g = lane >> 4;
  const int fk = g * 8;
  short* Pw = &P[w][0];

  const int L0 = w * 64 + lane, L1 = L0 + 256;
  const int r0 = L0 >> 3, c0 = (L0 & 7) ^ (r0 & 7);
  const int r1 = L1 >> 3, c1 = (L1 & 7) ^ (r1 & 7);
  const short* kg0 = qkv + (size_t)(b * Ss + r0) * 3072 + 1024 + h * 64 + c0 * 8;
  const short* kg1 = qkv + (size_t)(b * Ss + r1) * 3072 + 1024 + h * 64 + c1 * 8;
  const short* vg0 = Vt + (size_t)(bh * 64 + r0) * Ss + c0 * 8;
  const short* vg1 = Vt + (size_t)(bh * 64 + r1) * Ss + c1 * 8;

  short8 qf[2];
  {
    const short* qrow = qkv + (size_t)(b * Ss + qbase + q) * 3072 + h * 64;
    qf[0] = *(const short8*)(qrow + fk);
    qf[1] = *(const short8*)(qrow + 32 + fk);
  }
  float4v o[4] = {};
  float l_i = 0.f;
  const float sc = 0.125f * 1.44269504088896f;
  const int nkt = qb + 1;

  for (int kt = 0; kt < nkt; kt++) {
    const int kbase = kt * 64;
    __syncthreads();
    gl_lds16(kg0 + (size_t)kbase * 3072, Ks + L0 * 8);
    gl_lds16(kg1 + (size_t)kbase * 3072, Ks + L1 * 8);
    gl_lds16(vg0 + kbase, Vs + L0 * 8);
    gl_lds16(vg1 + kbase, Vs + L1 * 8);
    __syncthreads();

    short8 kf[4][2], vf[4][2];
#pragma unroll
    for (int t = 0; t < 4; t++) {
      const int row = 16 * t + q;
      const int sw = (g ^ (row & 7)) * 8;
      kf[t][0] = *(const short8*)(Ks + row * 64 + sw);
      kf[t][1] = *(const short8*)(Ks + row * 64 + (sw ^ 32));
      vf[t][0] = *(const short8*)(Vs + row * 64 + sw);
      vf[t][1] = *(const short8*)(Vs + row * 64 + (sw ^ 32));
    }
    float4v s[4] = {};
#pragma unroll
    for (int t = 0; t < 4; t++) {
      s[t] = MFMA(kf[t][0], qf[0], s[t]);
      s[t] = MFMA(kf[t][1], qf[1], s[t]);
    }
    const bool maskt = (kbase + 63 > qbase);
    const int qlim = qbase + q - kbase;
    float p[4][4];
    float rs = 0.f;
#pragma unroll
    for (int t = 0; t < 4; t++) {
#pragma unroll
      for (int r = 0; r < 4; r++) {
        float v = s[t][r] * sc;
        if (maskt && (16 * t + 4 * g + r > qlim)) v = -3.0e38f;
        float e = __builtin_amdgcn_exp2f(v);
        p[t][r] = e;
        rs += e;
      }
    }
    rs += __shfl_xor(rs, 16);
    rs += __shfl_xor(rs, 32);
    l_i += rs;
#pragma unroll
    for (int t = 0; t < 4; t++) {
      unsigned lo = (unsigned)(unsigned short)f2bf(p[t][0]) |
                    ((unsigned)(unsigned short)f2bf(p[t][1]) << 16);
      unsigned hi = (unsigned)(unsigned short)f2bf(p[t][2]) |
                    ((unsigned)(unsigned short)f2bf(p[t][3]) << 16);
      uint2 u; u.x = lo; u.y = hi;
      *(uint2*)(Pw + q * 72 + 16 * t + 4 * g) = u;
    }
    asm volatile("s_waitcnt lgkmcnt(0)" ::: "memory");
    short8 pb0 = *(const short8*)(Pw + q * 72 + fk);
    short8 pb1 = *(const short8*)(Pw + q * 72 + 32 + fk);
#pragma unroll
    for (int t = 0; t < 4; t++) {
      o[t] = MFMA(vf[t][0], pb0, o[t]);
      o[t] = MFMA(vf[t][1], pb1, o[t]);
    }
  }
  const float inv = 1.0f / l_i;
  const int orow = b * Ss + qbase + q;
#pragma unroll
  for (int t = 0; t < 4; t++) {
    short4v ov;
    ov.x = f2bf(o[t][0] * inv);
    ov.y = f2bf(o[t][1] * inv);
    ov.z = f2bf(o[t][2] * inv);
    ov.w = f2bf(o[t][3] * inv);
    *(short4v*)(att + (size_t)orow * Dd + h * 64 + 16 * t + 4 * g) = ov;
  }
}

extern "C" void kernel_launch(void* const* d_in, const int* in_sizes, int n_in,
                              void* d_out, int out_size, void* d_ws, size_t ws_size,
                              hipStream_t stream) {
  const float* x    = (const float*)d_in[0];
  const float* Wqkv = (const float*)d_in[1];
  const float* bqkv = (const float*)d_in[2];
  const float* Wo   = (const float*)d_in[3];
  const float* bo   = (const float*)d_in[4];
  const float* Wfc  = (const float*)d_in[5];
  const float* bfc  = (const float*)d_in[6];
  const float* Wpr  = (const float*)d_in[7];
  const float* bpr  = (const float*)d_in[8];
  const float* g1   = (const float*)d_in[9];
  const float* be1  = (const float*)d_in[10];
  const float* g2   = (const float*)d_in[11];
  const float* be2  = (const float*)d_in[12];

  char* ws = (char*)d_ws;
  const size_t MB = 1024 * 1024;
  short* h1     = (short*)(ws + 0);        // [0,8)
  short* qkvb   = (short*)(ws + 8 * MB);   // [8,32)
  short* partWo = (short*)(ws + 0);        // [0,16), after flash
  short* partPr = (short*)(ws + 0);        // [0,16), after fc
  short* Vt     = (short*)(ws + 32 * MB);  // [32,40)
  short* att    = (short*)(ws + 40 * MB);  // [40,48)
  float* x1     = (float*)(ws + 48 * MB);  // [48,64)
  short* h2     = (short*)(ws + 64 * MB);  // [64,72)
  short* geluo  = (short*)(ws + 72 * MB);  // [72,104)
  short* WtQkv  = (short*)(ws + 104 * MB);
  short* WtO    = (short*)(ws + 110 * MB);
  short* WtFc   = (short*)(ws + 112 * MB);
  short* WtPr   = (short*)(ws + 120 * MB);

  prep_kernel<<<16384, 256, 0, stream>>>(Wqkv, WtQkv, Wo, WtO, Wfc, WtFc,
                                         Wpr, WtPr, x, g1, be1, h1);
  k_gemm_qkv<<<768, 256, 0, stream>>>(h1, WtQkv, bqkv, qkvb);
  vt_kernel<<<dim3(64, 2, 32), 256, 0, stream>>>(qkvb, Vt);
  flash_kernel<<<1024, 256, 0, stream>>>(qkvb, Vt, att);
  k_gemm_wo<<<512, 256, 0, stream>>>(att, WtO, partWo);
  reduce_ln_kernel<<<4096, 256, 0, stream>>>(x, bo, partWo, g2, be2, x1, h2);
  k_gemm_fc<<<1024, 256, 0, stream>>>(h2, WtFc, bfc, geluo);
  k_gemm_pr<<<512, 256, 0, stream>>>(geluo, WtPr, partPr);
  reduce_kernel<<<4096, 256, 0, stream>>>(x1, bpr, partPr, (float*)d_out);
}

// Round 9
// 294.935 us; speedup vs baseline: 2.1818x; 1.1216x over previous
//
#include <hip/hip_runtime.h>
#include <cstdint>
#include <cstddef>

#define Bb 2
#define Ss 2048
#define Dd 1024
#define Hh 16

typedef __attribute__((ext_vector_type(8))) short short8;
typedef __attribute__((ext_vector_type(4))) short short4v;
typedef __attribute__((ext_vector_type(4))) float float4v;

__device__ inline short f2bf(float f) {
  unsigned u = __builtin_bit_cast(unsigned, f);
  u = (u + 0x7fffu + ((u >> 16) & 1u)) >> 16;
  return (short)u;
}

__device__ inline float bf2f(short s) {
  unsigned u = ((unsigned)(unsigned short)s) << 16;
  return __builtin_bit_cast(float, u);
}

__device__ inline void gl_lds16(const void* g, void* l) {
  __builtin_amdgcn_global_load_lds(
      (__attribute__((address_space(1))) void*)(void*)(g),
      (__attribute__((address_space(3))) void*)(l), 16, 0, 0);
}

#define MFMA(a, b, c) __builtin_amdgcn_mfma_f32_16x16x32_bf16((a), (b), (c), 0, 0, 0)

// ---------------- LN row body (f32 in -> bf16 out) ----------------
__device__ __forceinline__ void ln_row(const float* __restrict__ x,
                                       const float* __restrict__ g,
                                       const float* __restrict__ be,
                                       short* __restrict__ out, int row,
                                       float* red) {
  int tid = threadIdx.x;
  const float4* xr = (const float4*)(x + (size_t)row * Dd);
  float4 v = xr[tid];
  float s = v.x + v.y + v.z + v.w;
  float q = v.x * v.x + v.y * v.y + v.z * v.z + v.w * v.w;
#pragma unroll
  for (int off = 1; off < 64; off <<= 1) {
    s += __shfl_xor(s, off);
    q += __shfl_xor(q, off);
  }
  int w = tid >> 6;
  if ((tid & 63) == 0) { red[w] = s; red[4 + w] = q; }
  __syncthreads();
  s = red[0] + red[1] + red[2] + red[3];
  q = red[4] + red[5] + red[6] + red[7];
  float mu = s * (1.0f / Dd);
  float var = q * (1.0f / Dd) - mu * mu;
  float rstd = rsqrtf(var + 1e-5f);
  float4 gv = ((const float4*)g)[tid], bv = ((const float4*)be)[tid];
  short4v o;
  o.x = f2bf((v.x - mu) * rstd * gv.x + bv.x);
  o.y = f2bf((v.y - mu) * rstd * gv.y + bv.y);
  o.z = f2bf((v.z - mu) * rstd * gv.z + bv.z);
  o.w = f2bf((v.w - mu) * rstd * gv.w + bv.w);
  *(short4v*)(out + (size_t)row * Dd + tid * 4) = o;
}

// ---------------- prep: 4 weight transposes + LN1, by block range ------------
__global__ __launch_bounds__(256) void prep_kernel(
    const float* __restrict__ W0, short* __restrict__ T0,
    const float* __restrict__ W1, short* __restrict__ T1,
    const float* __restrict__ W2, short* __restrict__ T2,
    const float* __restrict__ W3, short* __restrict__ T3,
    const float* __restrict__ x, const float* __restrict__ g1,
    const float* __restrict__ be1, short* __restrict__ h1) {
  __shared__ __align__(16) float t[32][33];
  int id = blockIdx.x;
  if (id >= 12288) {
    ln_row(x, g1, be1, h1, id - 12288, &t[0][0]);
    return;
  }
  const float* W; short* Wt; int N, K, tix;
  if (id < 3072)      { W = W0; Wt = T0; N = 3072; K = 1024; tix = id; }
  else if (id < 4096) { W = W1; Wt = T1; N = 1024; K = 1024; tix = id - 3072; }
  else if (id < 8192) { W = W2; Wt = T2; N = 4096; K = 1024; tix = id - 4096; }
  else                { W = W3; Wt = T3; N = 1024; K = 4096; tix = id - 8192; }
  int nx = N / 32;
  int n0 = (tix % nx) * 32, k0 = (tix / nx) * 32;
  int tx = threadIdx.x & 31, ty = threadIdx.x >> 5;
#pragma unroll
  for (int i = 0; i < 4; i++)
    t[ty + 8 * i][tx] = W[(size_t)(k0 + ty + 8 * i) * N + n0 + tx];
  __syncthreads();
#pragma unroll
  for (int i = 0; i < 4; i++)
    Wt[(size_t)(n0 + ty + 8 * i) * K + k0 + tx] = f2bf(t[tx][ty + 8 * i]);
}

// -------- fused: x1 = x + bias + p0 + p1 (f32), then h2 = LN2(x1) bf16 -------
__global__ __launch_bounds__(256) void reduce_ln_kernel(const float* __restrict__ x,
                                                        const float* __restrict__ bias,
                                                        const short* __restrict__ parts,
                                                        const float* __restrict__ g,
                                                        const float* __restrict__ be,
                                                        float* __restrict__ x1,
                                                        short* __restrict__ h2) {
  int row = blockIdx.x, tid = threadIdx.x;
  size_t base = (size_t)row * Dd + tid * 4;
  float4 v = *(const float4*)(x + base);
  float4 bv = ((const float4*)bias)[tid];
  v.x += bv.x; v.y += bv.y; v.z += bv.z; v.w += bv.w;
#pragma unroll
  for (int s = 0; s < 2; s++) {
    short4v p = *(const short4v*)(parts + (size_t)s * 4096 * Dd + base);
    v.x += bf2f(p.x); v.y += bf2f(p.y); v.z += bf2f(p.z); v.w += bf2f(p.w);
  }
  *(float4*)(x1 + base) = v;
  float s = v.x + v.y + v.z + v.w;
  float q = v.x * v.x + v.y * v.y + v.z * v.z + v.w * v.w;
#pragma unroll
  for (int off = 1; off < 64; off <<= 1) {
    s += __shfl_xor(s, off);
    q += __shfl_xor(q, off);
  }
  __shared__ float as_[4], aq_[4];
  int w = tid >> 6;
  if ((tid & 63) == 0) { as_[w] = s; aq_[w] = q; }
  __syncthreads();
  s = as_[0] + as_[1] + as_[2] + as_[3];
  q = aq_[0] + aq_[1] + aq_[2] + aq_[3];
  float mu = s * (1.0f / Dd);
  float var = q * (1.0f / Dd) - mu * mu;
  float rstd = rsqrtf(var + 1e-5f);
  float4 gv = ((const float4*)g)[tid], b2 = ((const float4*)be)[tid];
  short4v o;
  o.x = f2bf((v.x - mu) * rstd * gv.x + b2.x);
  o.y = f2bf((v.y - mu) * rstd * gv.y + b2.y);
  o.z = f2bf((v.z - mu) * rstd * gv.z + b2.z);
  o.w = f2bf((v.w - mu) * rstd * gv.w + b2.w);
  *(short4v*)(h2 + base) = o;
}

// ---------------- final reduce: dst = src + bias + sum(2 bf16 partials) ------
__global__ __launch_bounds__(256) void reduce_kernel(const float* __restrict__ src,
                                                     const float* __restrict__ bias,
                                                     const short* __restrict__ parts,
                                                     float* __restrict__ dst) {
  int row = blockIdx.x, tid = threadIdx.x;
  size_t base = (size_t)row * Dd + tid * 4;
  float4 v = *(const float4*)(src + base);
  float4 bv = ((const float4*)bias)[tid];
  v.x += bv.x; v.y += bv.y; v.z += bv.z; v.w += bv.w;
#pragma unroll
  for (int s = 0; s < 2; s++) {
    short4v p = *(const short4v*)(parts + (size_t)s * 4096 * Dd + base);
    v.x += bf2f(p.x); v.y += bf2f(p.y); v.z += bf2f(p.z); v.w += bf2f(p.w);
  }
  *(float4*)(dst + base) = v;
}

// ---------------- 128x128 bf16 MFMA GEMM tile, BK=64, XOR-swizzled LDS -------
// Early-issue prefetch: barrier -> ds_read all frags -> barrier -> issue next
// staging -> MFMA.  Next iteration's barrier drains staging issued a full
// compute phase earlier (latency hidden, no extra LDS).
// MODE 2: bf16 out = gelu(acc+bias); MODE 3: bf16 partial at outp + zp*M*N;
// MODE 4: bf16 out = acc+bias, plus transposed Vt write for cols >= 2048.
template <int MODE>
__device__ __forceinline__ void gemm_tile(const short* __restrict__ A,
                                          const short* __restrict__ Bt,
                                          const float* __restrict__ bias,
                                          void* __restrict__ outp,
                                          short* __restrict__ vtp,
                                          int M, int N, int K,
                                          int m0, int n0, int zp,
                                          int ks, int ke, char* smem) {
  short* As = (short*)smem;
  short* Bs = (short*)smem + 128 * 64;
  const int tid = threadIdx.x;
  const int w = tid >> 6, lane = tid & 63;
  const int sr = lane >> 3;
  const int sc = lane & 7;
  const int gc = sc ^ sr;
  const int fr = lane & 15;
  const int g = lane >> 4;
  const int wm = (w >> 1) * 64, wn = (w & 1) * 64;
  float4v acc[4][4] = {};
  const short* Ag = A + (size_t)(m0 + w * 32 + sr) * K + gc * 8;
  const short* Bg = Bt + (size_t)(n0 + w * 32 + sr) * K + gc * 8;
  short* Asw = As + (w * 32 + sr) * 64 + sc * 8;
  short* Bsw = Bs + (w * 32 + sr) * 64 + sc * 8;
  // prologue staging for k0 = ks
#pragma unroll
  for (int i = 0; i < 4; i++) {
    gl_lds16(Ag + (size_t)(i * 8) * K + ks, Asw + i * 8 * 64);
    gl_lds16(Bg + (size_t)(i * 8) * K + ks, Bsw + i * 8 * 64);
  }
  for (int k0 = ks; k0 < ke; k0 += 64) {
    __syncthreads();  // staging for k0 complete (drains vmcnt)
    short8 a[2][4], b[2][4];
#pragma unroll
    for (int kh = 0; kh < 2; kh++) {
#pragma unroll
      for (int i = 0; i < 4; i++) {
        int row = wm + i * 16 + fr;
        int slot = (g + kh * 4) ^ (row & 7);
        a[kh][i] = *(const short8*)(As + row * 64 + slot * 8);
      }
#pragma unroll
      for (int j = 0; j < 4; j++) {
        int row = wn + j * 16 + fr;
        int slot = (g + kh * 4) ^ (row & 7);
        b[kh][j] = *(const short8*)(Bs + row * 64 + slot * 8);
      }
    }
    __syncthreads();  // all waves have their frags in registers
    if (k0 + 64 < ke) {
#pragma unroll
      for (int i = 0; i < 4; i++) {
        gl_lds16(Ag + (size_t)(i * 8) * K + k0 + 64, Asw + i * 8 * 64);
        gl_lds16(Bg + (size_t)(i * 8) * K + k0 + 64, Bsw + i * 8 * 64);
      }
    }
#pragma unroll
    for (int kh = 0; kh < 2; kh++)
#pragma unroll
      for (int i = 0; i < 4; i++)
#pragma unroll
        for (int j = 0; j < 4; j++)
          acc[kh & 0 ? 0 : i][j] = MFMA(a[kh][i], b[kh][j], acc[i][j]);
  }
  const int crow = g * 4;
  const int ccol = fr;
#pragma unroll
  for (int i = 0; i < 4; i++) {
#pragma unroll
    for (int j = 0; j < 4; j++) {
      int col = n0 + wn + j * 16 + ccol;
      float bcol = (MODE == 3) ? 0.f : bias[col];
      short sh[4];
#pragma unroll
      for (int r = 0; r < 4; r++) {
        int row = m0 + wm + i * 16 + crow + r;
        float v = acc[i][j][r] + bcol;
        if (MODE == 4) {
          sh[r] = f2bf(v);
          ((short*)outp)[(size_t)row * N + col] = sh[r];
        } else if (MODE == 2) {
          float y = 0.79788456f * (v + 0.044715f * v * v * v);
          float e = __builtin_amdgcn_exp2f(y * 2.885390082f);
          float th = 1.0f - 2.0f * __builtin_amdgcn_rcpf(e + 1.0f);
          v = 0.5f * v * (1.0f + th);
          ((short*)outp)[(size_t)row * N + col] = f2bf(v);
        } else {
          short* pp = (short*)outp + (size_t)zp * M * N;
          pp[(size_t)row * N + col] = f2bf(v);
        }
      }
      if (MODE == 4 && col >= 2048) {
        // transposed V write: Vt[(bh*64+d)*Ss + s], 4 consecutive s per lane
        int hd = col - 2048;
        int rbase = m0 + wm + i * 16 + crow;
        int bq = rbase >> 11, sb = rbase & 2047;
        int bh = bq * 16 + (hd >> 6), d = hd & 63;
        short4v pk;
        pk.x = sh[0]; pk.y = sh[1]; pk.z = sh[2]; pk.w = sh[3];
        *(short4v*)(vtp + (size_t)(bh * 64 + d) * Ss + sb) = pk;
      }
    }
  }
}

// ---------------- qkv GEMM (+fused V transpose): 768 blocks, 8m x 12n patch --
__global__ __launch_bounds__(256) void k_gemm_qkv(const short* __restrict__ A,
                                                  const short* __restrict__ Bt,
                                                  const float* __restrict__ bias,
                                                  short* __restrict__ o,
                                                  short* __restrict__ Vt) {
  __shared__ __align__(16) char smem[32768];
  int t = blockIdx.x;
  int c8 = t & 7, tt = t >> 3;
  int m0 = ((c8 >> 1) * 8 + tt / 12) * 128;
  int n0 = ((c8 & 1) * 12 + tt % 12) * 128;
  gemm_tile<4>(A, Bt, bias, o, Vt, 4096, 3072, 1024, m0, n0, 0, 0, 1024, smem);
}

// ---------------- fc GEMM+GELU: 1024 blocks, per-XCD 8m x 16n patch ----------
__global__ __launch_bounds__(256) void k_gemm_fc(const short* __restrict__ A,
                                                 const short* __restrict__ Bt,
                                                 const float* __restrict__ bias,
                                                 short* __restrict__ o) {
  __shared__ __align__(16) char smem[32768];
  int t = blockIdx.x;
  int c8 = t & 7, tt = t >> 3;
  int m0 = ((c8 >> 1) * 8 + tt / 16) * 128;
  int n0 = ((c8 & 1) * 16 + tt % 16) * 128;
  gemm_tile<2>(A, Bt, bias, o, nullptr, 4096, 4096, 1024, m0, n0, 0, 0, 1024, smem);
}

// ---------------- wo projection: 512 blocks, split-K=2, 4m x 8n patch --------
__global__ __launch_bounds__(256) void k_gemm_wo(const short* __restrict__ A,
                                                 const short* __restrict__ Bt,
                                                 short* __restrict__ parts) {
  __shared__ __align__(16) char smem[32768];
  int c = blockIdx.x;
  int z = c >> 8, rem = c & 255;
  int c8 = rem & 7, tt = rem >> 3;
  int m0 = (c8 * 4 + tt / 8) * 128, n0 = (tt % 8) * 128;
  gemm_tile<3>(A, Bt, nullptr, parts, nullptr, 4096, 1024, 1024, m0, n0, z,
               z * 512, z * 512 + 512, smem);
}

// ---------------- pr projection: 512 blocks, split-K=2, 4m x 8n patch --------
__global__ __launch_bounds__(256) void k_gemm_pr(const short* __restrict__ A,
                                                 const short* __restrict__ Bt,
                                                 short* __restrict__ parts) {
  __shared__ __align__(16) char smem[32768];
  int c = blockIdx.x;
  int z = c >> 8, rem = c & 255;
  int c8 = rem & 7, tt = rem >> 3;
  int m0 = (c8 * 4 + tt / 8) * 128, n0 = (tt % 8) * 128;
  gemm_tile<3>(A, Bt, nullptr, parts, nullptr, 4096, 1024, 4096, m0, n0, z,
               z * 2048, z * 2048 + 2048, smem);
}

// ---------------- flash attention, early-issue prefetch staging --------------
__global__ __launch_bounds__(256) void flash_kernel(const short* __restrict__ qkv,
                                                    const short* __restrict__ Vt,
                                                    short* __restrict__ att) {
  __shared__ __align__(16) short Ks[4096];
  __shared__ __align__(16) short Vs[4096];
  __shared__ __align__(16) short P[4][16 * 72];
  const int w = threadIdx.x >> 6, lane = threadIdx.x & 63;
  const int qb = 31 - (blockIdx.x >> 5);
  const int bh = blockIdx.x & 31;
  const int b = bh >> 4, h = bh & 15;
  const int qbase = qb * 64 + w * 16;
  const int q = lane & 15;
  const int g = lane >> 4;
  const int fk = g * 8;
  short* Pw = &P[w][0];

  const int L0 = w * 64 + lane, L1 = L0 + 256;
  const int r0 = L0 >> 3, c0 = (L0 & 7) ^ (r0 & 7);
  const int r1 = L1 >> 3, c1 = (L1 & 7) ^ (r1 & 7);
  const short* kg0 = qkv + (size_t)(b * Ss + r0) * 3072 + 1024 + h * 64 + c0 * 8;
  const short* kg1 = qkv + (size_t)(b * Ss + r1) * 3072 + 1024 + h * 64 + c1 * 8;
  const short* vg0 = Vt + (size_t)(bh * 64 + r0) * Ss + c0 * 8;
  const short* vg1 = Vt + (size_t)(bh * 64 + r1) * Ss + c1 * 8;

  short8 qf[2];
  {
    const short* qrow = qkv + (size_t)(b * Ss + qbase + q) * 3072 + h * 64;
    qf[0] = *(const short8*)(qrow + fk);
    qf[1] = *(const short8*)(qrow + 32 + fk);
  }
  float4v o[4] = {};
  float l_i = 0.f;
  const float sc = 0.125f * 1.44269504088896f;
  const int nkt = qb + 1;

  // prologue staging for kt = 0
  gl_lds16(kg0, Ks + L0 * 8);
  gl_lds16(kg1, Ks + L1 * 8);
  gl_lds16(vg0, Vs + L0 * 8);
  gl_lds16(vg1, Vs + L1 * 8);

  for (int kt = 0; kt < nkt; kt++) {
    const int kbase = kt * 64;
    __syncthreads();  // staging for kt complete

    short8 kf[4][2], vf[4][2];
#pragma unroll
    for (int t = 0; t < 4; t++) {
      const int row = 16 * t + q;
      const int sw = (g ^ (row & 7)) * 8;
      kf[t][0] = *(const short8*)(Ks + row * 64 + sw);
      kf[t][1] = *(const short8*)(Ks + row * 64 + (sw ^ 32));
      vf[t][0] = *(const short8*)(Vs + row * 64 + sw);
      vf[t][1] = *(const short8*)(Vs + row * 64 + (sw ^ 32));
    }
    __syncthreads();  // all waves consumed Ks/Vs
    if (kt + 1 < nkt) {
      const size_t nb = (size_t)(kbase + 64);
      gl_lds16(kg0 + nb * 3072, Ks + L0 * 8);
      gl_lds16(kg1 + nb * 3072, Ks + L1 * 8);
      gl_lds16(vg0 + nb, Vs + L0 * 8);
      gl_lds16(vg1 + nb, Vs + L1 * 8);
    }

    float4v s[4] = {};
#pragma unroll
    for (int t = 0; t < 4; t++) {
      s[t] = MFMA(kf[t][0], qf[0], s[t]);
      s[t] = MFMA(kf[t][1], qf[1], s[t]);
    }
    const bool maskt = (kbase + 63 > qbase);
    const int qlim = qbase + q - kbase;
    float p[4][4];
    float rs = 0.f;
#pragma unroll
    for (int t = 0; t < 4; t++) {
#pragma unroll
      for (int r = 0; r < 4; r++) {
        float v = s[t][r] * sc;
        if (maskt && (16 * t + 4 * g + r > qlim)) v = -3.0e38f;
        float e = __builtin_amdgcn_exp2f(v);
        p[t][r] = e;
        rs += e;
      }
    }
    rs += __shfl_xor(rs, 16);
    rs += __shfl_xor(rs, 32);
    l_i += rs;
#pragma unroll
    for (int t = 0; t < 4; t++) {
      unsigned lo = (unsigned)(unsigned short)f2bf(p[t][0]) |
                    ((unsigned)(unsigned short)f2bf(p[t][1]) << 16);
      unsigned hi = (unsigned)(unsigned short)f2bf(p[t][2]) |
                    ((unsigned)(unsigned short)f2bf(p[t][3]) << 16);
      uint2 u; u.x = lo; u.y = hi;
      *(uint2*)(Pw + q * 72 + 16 * t + 4 * g) = u;
    }
    asm volatile("s_waitcnt lgkmcnt(0)" ::: "memory");
    short8 pb0 = *(const short8*)(Pw + q * 72 + fk);
    short8 pb1 = *(const short8*)(Pw + q * 72 + 32 + fk);
#pragma unroll
    for (int t = 0; t < 4; t++) {
      o[t] = MFMA(vf[t][0], pb0, o[t]);
      o[t] = MFMA(vf[t][1], pb1, o[t]);
    }
  }
  const float inv = 1.0f / l_i;
  const int orow = b * Ss + qbase + q;
#pragma unroll
  for (int t = 0; t < 4; t++) {
    short4v ov;
    ov.x = f2bf(o[t][0] * inv);
    ov.y = f2bf(o[t][1] * inv);
    ov.z = f2bf(o[t][2] * inv);
    ov.w = f2bf(o[t][3] * inv);
    *(short4v*)(att + (size_t)orow * Dd + h * 64 + 16 * t + 4 * g) = ov;
  }
}

extern "C" void kernel_launch(void* const* d_in, const int* in_sizes, int n_in,
                              void* d_out, int out_size, void* d_ws, size_t ws_size,
                              hipStream_t stream) {
  const float* x    = (const float*)d_in[0];
  const float* Wqkv = (const float*)d_in[1];
  const float* bqkv = (const float*)d_in[2];
  const float* Wo   = (const float*)d_in[3];
  const float* bo   = (const float*)d_in[4];
  const float* Wfc  = (const float*)d_in[5];
  const float* bfc  = (const float*)d_in[6];
  const float* Wpr  = (const float*)d_in[7];
  const float* bpr  = (const float*)d_in[8];
  const float* g1   = (const float*)d_in[9];
  const float* be1  = (const float*)d_in[10];
  const float* g2   = (const float*)d_in[11];
  const float* be2  = (const float*)d_in[12];

  char* ws = (char*)d_ws;
  const size_t MB = 1024 * 1024;
  short* h1     = (short*)(ws + 0);        // [0,8)
  short* qkvb   = (short*)(ws + 8 * MB);   // [8,32)
  short* partWo = (short*)(ws + 0);        // [0,16), after flash
  short* partPr = (short*)(ws + 0);        // [0,16), after fc
  short* Vt     = (short*)(ws + 32 * MB);  // [32,40)
  short* att    = (short*)(ws + 40 * MB);  // [40,48)
  float* x1     = (float*)(ws + 48 * MB);  // [48,64)
  short* h2     = (short*)(ws + 64 * MB);  // [64,72)
  short* geluo  = (short*)(ws + 72 * MB);  // [72,104)
  short* WtQkv  = (short*)(ws + 104 * MB);
  short* WtO    = (short*)(ws + 110 * MB);
  short* WtFc   = (short*)(ws + 112 * MB);
  short* WtPr   = (short*)(ws + 120 * MB);

  prep_kernel<<<16384, 256, 0, stream>>>(Wqkv, WtQkv, Wo, WtO, Wfc, WtFc,
                                         Wpr, WtPr, x, g1, be1, h1);
  k_gemm_qkv<<<768, 256, 0, stream>>>(h1, WtQkv, bqkv, qkvb, Vt);
  flash_kernel<<<1024, 256, 0, stream>>>(qkvb, Vt, att);
  k_gemm_wo<<<512, 256, 0, stream>>>(att, WtO, partWo);
  reduce_ln_kernel<<<4096, 256, 0, stream>>>(x, bo, partWo, g2, be2, x1, h2);
  k_gemm_fc<<<1024, 256, 0, stream>>>(h2, WtFc, bfc, geluo);
  k_gemm_pr<<<512, 256, 0, stream>>>(geluo, WtPr, partPr);
  reduce_kernel<<<4096, 256, 0, stream>>>(x1, bpr, partPr, (float*)d_out);
}